// Round 3
// baseline (398.450 us; speedup 1.0000x reference)
//
#include <hip/hip_runtime.h>
#include <cstdint>

#define B_SZ 8192
#define IN_SZ 1024
#define H_SZ 1024

typedef unsigned short u16;
typedef __bf16 bf16_t;
typedef bf16_t bf16x8 __attribute__((ext_vector_type(8)));
typedef float floatx4 __attribute__((ext_vector_type(4)));

__device__ __forceinline__ u16 f2bf(float f) {
    unsigned int u = __float_as_uint(f);
    u += 0x7fffu + ((u >> 16) & 1u);   // RNE
    return (u16)(u >> 16);
}

// async global->LDS, 16B per lane; LDS dest = wave-uniform base + lane*16
__device__ __forceinline__ void g2l16(const u16* g, u16* l) {
    __builtin_amdgcn_global_load_lds(
        (__attribute__((address_space(1))) void*)(uintptr_t)g,
        (__attribute__((address_space(3))) void*)(uint32_t)(uintptr_t)l,
        16, 0, 0);
}

// ---------------- fused fp32 -> bf16 conversion (one launch for all 8 tensors) ----
__global__ __launch_bounds__(256) void cvt_all(
    const float* __restrict__ x, const float* __restrict__ h,
    const float* __restrict__ w0, const float* __restrict__ w1,
    const float* __restrict__ w2, const float* __restrict__ w3,
    const float* __restrict__ w4, const float* __restrict__ w5,
    u16* __restrict__ dx, u16* __restrict__ dh,
    u16* __restrict__ dw0, u16* __restrict__ dw1, u16* __restrict__ dw2,
    u16* __restrict__ dw3, u16* __restrict__ dw4, u16* __restrict__ dw5) {
    const int b = blockIdx.x;
    const float* s;
    u16* d;
    int off;
    if (b < 8192) {
        s = x; d = dx; off = (b << 8) + threadIdx.x;
    } else if (b < 16384) {
        s = h; d = dh; off = ((b - 8192) << 8) + threadIdx.x;
    } else {
        const int wb = b - 16384;
        const int w = wb >> 10;
        off = ((wb & 1023) << 8) + threadIdx.x;
        switch (w) {
            case 0: s = w0; d = dw0; break;
            case 1: s = w1; d = dw1; break;
            case 2: s = w2; d = dw2; break;
            case 3: s = w3; d = dw3; break;
            case 4: s = w4; d = dw4; break;
            default: s = w5; d = dw5; break;
        }
    }
    float4 v = ((const float4*)s)[off];
    ushort4 o;
    o.x = f2bf(v.x); o.y = f2bf(v.y); o.z = f2bf(v.z); o.w = f2bf(v.w);
    ((ushort4*)d)[off] = o;
}

// ---------------- fused two-segment NT GEMM + gate epilogue ----------------
// 256x128 tile, BK=64, 8 waves (512 thr), 2-barrier body (stage->sync->compute->sync).
// Per-wave shape identical to the round-0 proven body: 4x4 acc of 16x16x32 MFMA,
// wave grid 4x2 (wr in 0..3 -> 64-row strip, wc in 0..1 -> 64-col strip).
// K-slices (BK=64 = 2x32) computed sequentially to keep VGPR ~124 (4 waves/SIMD ->
// 2 blocks/CU). Do NOT add dbuf/launch_bounds(,N): round-1 showed -42%.
// C[m,n] = sum_k A0[m,k]*B0[n,k] + sum_k A1[m,k]*B1[n,k]   (K=1024 per segment)
// MODE 0 (fused r+z, N=2048): col<1024 -> out_rh=bf16(sigmoid(C+b)*hidden);
//                             col>=1024 -> out_f[.,c-1024]=sigmoid(C+b)
// MODE 2 (h~): ht = tanh(C+b); out_f = z*hidden + (1-z)*ht
template <int MODE, int LNBN>
__global__ __launch_bounds__(512) void gemm_gate(
    const u16* __restrict__ A0, const u16* __restrict__ B0,
    const u16* __restrict__ A1, const u16* __restrict__ B1,
    const float* __restrict__ bx0, const float* __restrict__ bh0,
    const float* __restrict__ bx1, const float* __restrict__ bh1,
    const float* __restrict__ hidden, const float* __restrict__ zbuf,
    u16* __restrict__ out_rh, float* __restrict__ out_f) {
    constexpr int BM = 256, BN = 128, BK = 64, K = 1024;
    __shared__ u16 As[BM * BK];   // 32 KB, row-major [256][64], linear (global_load_lds)
    __shared__ u16 Bs[BN * BK];   // 16 KB
    const int tid = threadIdx.x;
    const int wave = tid >> 6;
    const int lane = tid & 63;
    // chunked XCD swizzle (T1): gridDim.x % 8 == 0 (512 / 256: ok)
    const int nwg = gridDim.x;
    const int wid = blockIdx.x;
    const int swz = (wid & 7) * (nwg >> 3) + (wid >> 3);
    const int bn = swz & ((1 << LNBN) - 1);
    const int bm = swz >> LNBN;
    const int wr = wave >> 1, wc = wave & 1;   // 4x2 wave grid, 64x64 per wave

    const floatx4 z4 = {0.f, 0.f, 0.f, 0.f};
    floatx4 acc[4][4];
#pragma unroll
    for (int i = 0; i < 4; ++i)
#pragma unroll
        for (int j = 0; j < 4; ++j) acc[i][j] = z4;

    const u16* Aseg[2] = {A0, A1};
    const u16* Bseg[2] = {B0, B1};
    const int mr = lane & 15;
    const int q8 = (lane >> 4) * 8;

    for (int seg = 0; seg < 2; ++seg) {
        const u16* __restrict__ Ag = Aseg[seg];
        const u16* __restrict__ Bg = Bseg[seg];
        for (int kt = 0; kt < K / BK; ++kt) {
            const int k0 = kt * BK;
            // stage A tile: 2048 16B-chunks over 512 threads -> 4 per thread
            // chunk c: row=c>>3 (8 chunks/128B row), kslot=c&7
#pragma unroll
            for (int j = 0; j < 4; ++j) {
                const int c = j * 512 + wave * 64 + lane;
                g2l16(Ag + (size_t)(bm * BM + (c >> 3)) * K + k0 + (c & 7) * 8,
                      &As[(j * 512 + wave * 64) * 8]);
            }
            // stage B tile: 1024 chunks -> 2 per thread
#pragma unroll
            for (int j = 0; j < 2; ++j) {
                const int c = j * 512 + wave * 64 + lane;
                g2l16(Bg + (size_t)(bn * BN + (c >> 3)) * K + k0 + (c & 7) * 8,
                      &Bs[(j * 512 + wave * 64) * 8]);
            }
            __syncthreads();  // drains vmcnt: LDS tiles ready
            // two K-slices of 32, sequential to bound register pressure
#pragma unroll
            for (int s = 0; s < 2; ++s) {
                bf16x8 af[4], bv[4];
#pragma unroll
                for (int i = 0; i < 4; ++i)
                    af[i] = *(const bf16x8*)&As[(wr * 64 + i * 16 + mr) * BK + s * 32 + q8];
#pragma unroll
                for (int j = 0; j < 4; ++j)
                    bv[j] = *(const bf16x8*)&Bs[(wc * 64 + j * 16 + mr) * BK + s * 32 + q8];
#pragma unroll
                for (int i = 0; i < 4; ++i)
#pragma unroll
                    for (int j = 0; j < 4; ++j)
                        acc[i][j] = __builtin_amdgcn_mfma_f32_16x16x32_bf16(
                            af[i], bv[j], acc[i][j], 0, 0, 0);
            }
            __syncthreads();  // protect LDS before next stage overwrites
        }
    }

    // epilogue: C/D layout col=lane&15, row=(lane>>4)*4+reg (m89/m91 verified)
    const int colBase = bn * BN + wc * 64 + (lane & 15);
    const int rowBase = bm * BM + wr * 64 + (lane >> 4) * 4;
    if constexpr (MODE == 0) {
        const bool is_r = (colBase < H_SZ);   // block-uniform: boundary % BN == 0
#pragma unroll
        for (int j = 0; j < 4; ++j) {
            const int coln = colBase + j * 16;
            const int cb = is_r ? coln : coln - H_SZ;
            const float bias = is_r ? (bx0[cb] + bh0[cb]) : (bx1[cb] + bh1[cb]);
#pragma unroll
            for (int i = 0; i < 4; ++i) {
#pragma unroll
                for (int r = 0; r < 4; ++r) {
                    const int rown = rowBase + i * 16 + r;
                    const size_t idx = (size_t)rown * H_SZ + cb;
                    const float v = acc[i][j][r] + bias;
                    const float sg = 1.0f / (1.0f + __expf(-v));
                    if (is_r) {
                        out_rh[idx] = f2bf(sg * hidden[idx]);
                    } else {
                        out_f[idx] = sg;
                    }
                }
            }
        }
    } else {
#pragma unroll
        for (int j = 0; j < 4; ++j) {
            const int coln = colBase + j * 16;
            const float bias = bx0[coln] + bh0[coln];
#pragma unroll
            for (int i = 0; i < 4; ++i) {
#pragma unroll
                for (int r = 0; r < 4; ++r) {
                    const int rown = rowBase + i * 16 + r;
                    const size_t idx = (size_t)rown * H_SZ + coln;
                    const float v = acc[i][j][r] + bias;
                    const float ht = tanhf(v);
                    const float zz = zbuf[idx];
                    const float hh = hidden[idx];
                    out_f[idx] = zz * hh + (1.0f - zz) * ht;
                }
            }
        }
    }
}

// ---------------- row-wise log_softmax over H=1024 ----------------
__global__ __launch_bounds__(256) void lsm_kernel(const float* __restrict__ nh,
                                                  float* __restrict__ out) {
    const int row = blockIdx.x;
    const int tid = threadIdx.x;
    const int wave = tid >> 6, lane = tid & 63;
    const float4 v = ((const float4*)(nh + (size_t)row * H_SZ))[tid];
    __shared__ float redm[4];
    __shared__ float reds[4];
    float m = fmaxf(fmaxf(v.x, v.y), fmaxf(v.z, v.w));
#pragma unroll
    for (int o = 32; o; o >>= 1) m = fmaxf(m, __shfl_xor(m, o));
    if (lane == 0) redm[wave] = m;
    __syncthreads();
    const float M = fmaxf(fmaxf(redm[0], redm[1]), fmaxf(redm[2], redm[3]));
    float s = __expf(v.x - M) + __expf(v.y - M) + __expf(v.z - M) + __expf(v.w - M);
#pragma unroll
    for (int o = 32; o; o >>= 1) s += __shfl_xor(s, o);
    if (lane == 0) reds[wave] = s;
    __syncthreads();
    const float S = reds[0] + reds[1] + reds[2] + reds[3];
    const float lse = M + __logf(S);
    float4 ov;
    ov.x = v.x - lse; ov.y = v.y - lse; ov.z = v.z - lse; ov.w = v.w - lse;
    ((float4*)(out + (size_t)row * H_SZ))[tid] = ov;
}

extern "C" void kernel_launch(void* const* d_in, const int* in_sizes, int n_in,
                              void* d_out, int out_size, void* d_ws, size_t ws_size,
                              hipStream_t stream) {
    const float* input  = (const float*)d_in[0];
    const float* hidden = (const float*)d_in[1];
    const float* Wir = (const float*)d_in[2];  const float* bir = (const float*)d_in[3];
    const float* Whr = (const float*)d_in[4];  const float* bhr = (const float*)d_in[5];
    const float* Wiz = (const float*)d_in[6];  const float* biz = (const float*)d_in[7];
    const float* Whz = (const float*)d_in[8];  const float* bhz = (const float*)d_in[9];
    const float* Wih = (const float*)d_in[10]; const float* bih = (const float*)d_in[11];
    const float* Whh = (const float*)d_in[12]; const float* bhh = (const float*)d_in[13];

    // workspace layout (92 MB total)
    char* ws = (char*)d_ws;
    u16* Xb   = (u16*)(ws);                     // 16 MB  input bf16
    u16* Hb   = (u16*)(ws + (16u << 20));       // 16 MB  hidden bf16
    u16* Wrzx = (u16*)(ws + (32u << 20));       //  4 MB  concat(Wir, Wiz) [2048,1024]
    u16* Wrzh = (u16*)(ws + (36u << 20));       //  4 MB  concat(Whr, Whz) [2048,1024]
    u16* Whx  = (u16*)(ws + (40u << 20));       //  2 MB  Wih
    u16* Whhb = (u16*)(ws + (42u << 20));       //  2 MB  Whh
    u16* RHb  = (u16*)(ws + (44u << 20));       // 16 MB  r*hidden bf16
    float* Zf = (float*)(ws + (60u << 20));     // 32 MB  z f32

    float* out_lsm = (float*)d_out;
    float* out_nh  = (float*)d_out + (size_t)B_SZ * H_SZ;

    cvt_all<<<22528, 256, 0, stream>>>(
        input, hidden, Wir, Whr, Wiz, Whz, Wih, Whh,
        Xb, Hb,
        Wrzx,                       // Wir -> rows [0,1024) of rz-x
        Wrzh,                       // Whr -> rows [0,1024) of rz-h
        Wrzx + (1u << 20),          // Wiz -> rows [1024,2048)
        Wrzh + (1u << 20),          // Whz -> rows [1024,2048)
        Whx, Whhb);

    // fused r+z GEMM: N=2048, tiles 256x128 -> 16x32 = 512 blocks (2/CU)
    gemm_gate<0, 4><<<512, 512, 0, stream>>>(
        Xb, Wrzx, Hb, Wrzh, bir, bhr, biz, bhz, hidden, nullptr, RHb, Zf);
    // h~ GEMM: N=1024 -> 8x32 = 256 blocks (1/CU)
    gemm_gate<2, 3><<<256, 512, 0, stream>>>(
        Xb, Whx, RHb, Whhb, bih, bhh, nullptr, nullptr, hidden, Zf, nullptr, out_nh);

    lsm_kernel<<<B_SZ, 256, 0, stream>>>(out_nh, out_lsm);
}

// Round 4
// 342.905 us; speedup vs baseline: 1.1620x; 1.1620x over previous
//
#include <hip/hip_runtime.h>
#include <cstdint>

#define B_SZ 8192
#define IN_SZ 1024
#define H_SZ 1024

typedef unsigned short u16;
typedef __bf16 bf16_t;
typedef bf16_t bf16x8 __attribute__((ext_vector_type(8)));
typedef float floatx4 __attribute__((ext_vector_type(4)));

__device__ __forceinline__ u16 f2bf(float f) {
    unsigned int u = __float_as_uint(f);
    u += 0x7fffu + ((u >> 16) & 1u);   // RNE
    return (u16)(u >> 16);
}

__device__ __forceinline__ ushort4 cvt4(float4 v) {
    ushort4 o;
    o.x = f2bf(v.x); o.y = f2bf(v.y); o.z = f2bf(v.z); o.w = f2bf(v.w);
    return o;
}

// async global->LDS, 16B per lane; LDS dest = wave-uniform base + lane*16
__device__ __forceinline__ void g2l16(const u16* g, u16* l) {
    __builtin_amdgcn_global_load_lds(
        (__attribute__((address_space(1))) void*)(uintptr_t)g,
        (__attribute__((address_space(3))) void*)(uint32_t)(uintptr_t)l,
        16, 0, 0);
}

// ---------------- fused fp32 -> bf16 conversion into K-concat layouts -----------
// Acat[8192][2048] = [bf16(input) | bf16(hidden)]
// Brz [2048][2048] = [[Wir|Whr],[Wiz|Whz]]   (row n = output col n of r+z GEMM)
// Bh  [1024][2048] = [Wih|Whh]
// blocks [0,8192): input rows; [8192,16384): hidden rows; [16384,22528): weight rows
__global__ __launch_bounds__(256) void cvt_all(
    const float* __restrict__ x, const float* __restrict__ h,
    const float* __restrict__ Wir, const float* __restrict__ Whr,
    const float* __restrict__ Wiz, const float* __restrict__ Whz,
    const float* __restrict__ Wih, const float* __restrict__ Whh,
    u16* __restrict__ Acat, u16* __restrict__ Brz, u16* __restrict__ Bh) {
    const int b = blockIdx.x;
    const int t = threadIdx.x;
    if (b < 8192) {
        float4 v = ((const float4*)(x + (size_t)b * 1024))[t];
        ((ushort4*)(Acat + (size_t)b * 2048))[t] = cvt4(v);
    } else if (b < 16384) {
        const int m = b - 8192;
        float4 v = ((const float4*)(h + (size_t)m * 1024))[t];
        ((ushort4*)(Acat + (size_t)m * 2048 + 1024))[t] = cvt4(v);
    } else {
        const int wb = b - 16384;   // 0..6143
        const int w = wb >> 10;
        const int n = wb & 1023;
        const float* src;
        u16* dst;
        switch (w) {
            case 0: src = Wir; dst = Brz + (size_t)n * 2048;               break;
            case 1: src = Whr; dst = Brz + (size_t)n * 2048 + 1024;        break;
            case 2: src = Wiz; dst = Brz + (size_t)(n + 1024) * 2048;      break;
            case 3: src = Whz; dst = Brz + (size_t)(n + 1024) * 2048 + 1024; break;
            case 4: src = Wih; dst = Bh + (size_t)n * 2048;                break;
            default: src = Whh; dst = Bh + (size_t)n * 2048 + 1024;        break;
        }
        float4 v = ((const float4*)(src + (size_t)n * 1024))[t];
        ((ushort4*)dst)[t] = cvt4(v);
    }
}

// ---------------- K=2048 NT GEMM + gate epilogue, minimum-T3 dbuf ----------------
// BM=256, BK=64, 512 threads (8 waves), per-wave PN=64 cols, PM=256/(8/WN).
// A operand is split in K: k<1024 from A0 (stride sA0), k>=1024 from A1 (stride sA1).
// Pipeline (catalog T3-minimum, m230/m248 = 655-682 TF refcheck'd plain HIP):
//   STAGE(buf0,0); sync;
//   for t: STAGE(buf^1, t+1); COMPUTE(buf); sync; buf^=1;   // ONE drain per K-step
//   COMPUTE(buf)
// NO __launch_bounds__ min-waves (round-1 lesson: VGPR strangulation -42%).
// MODE 0 (r+z, N=2048): col<1024 -> out_rh=bf16(sigmoid(C+b)*hidden);
//                       col>=1024 -> out_zf[.,c-1024]=sigmoid(C+b)
// MODE 2 (h~, N=1024): ht=tanh(C+b); out_f = z*hidden + (1-z)*ht
template <int MODE, int BN, int LWN>
__global__ __launch_bounds__(512) void gemm2048(
    const u16* __restrict__ A0, const u16* __restrict__ A1,
    const int sA0, const int sA1,
    const u16* __restrict__ Bw,
    const float* __restrict__ bx0, const float* __restrict__ bh0,
    const float* __restrict__ bx1, const float* __restrict__ bh1,
    const float* __restrict__ hidden, const float* __restrict__ zbuf,
    u16* __restrict__ out_rh, float* __restrict__ out_zf,
    float* __restrict__ out_f) {
    constexpr int BM = 256, BK = 64, K = 2048, NKT = K / BK;
    constexpr int WN = 1 << LWN;            // waves along N
    constexpr int WM = 8 / WN;              // waves along M
    constexpr int PM = BM / WM;             // per-wave rows
    constexpr int PN = BN / WN;             // per-wave cols (=64 for both modes)
    constexpr int FM = PM / 16, FN = PN / 16;
    constexpr int AG = BM * BK / 8 / 512;   // A gloads per thread = 4
    constexpr int BG = BN * BK / 8 / 512;   // B gloads per thread

    __shared__ u16 As[2][BM * BK];          // 2 x 32 KB, linear [256][64]
    __shared__ u16 Bs[2][BN * BK];          // 2 x (BN/4) KB

    const int tid = threadIdx.x;
    const int wave = tid >> 6;
    const int lane = tid & 63;
    // chunked XCD swizzle (nwg = 256, % 8 == 0)
    const int nwg = gridDim.x;
    const int wid = blockIdx.x;
    const int swz = (wid & 7) * (nwg >> 3) + (wid >> 3);
    constexpr int NBN = (2048 / BN) * (MODE == 0 ? 1 : 1);  // bn count
    const int bn = swz & ((MODE == 0 ? (2048 / BN) : (1024 / BN)) - 1);
    const int bm = swz / (MODE == 0 ? (2048 / BN) : (1024 / BN));
    (void)NBN;
    const int wc = wave & (WN - 1);
    const int wr = wave >> LWN;

    const floatx4 z4 = {0.f, 0.f, 0.f, 0.f};
    floatx4 acc[FM][FN];
#pragma unroll
    for (int i = 0; i < FM; ++i)
#pragma unroll
        for (int j = 0; j < FN; ++j) acc[i][j] = z4;

    const int mr = lane & 15;
    const int q8 = (lane >> 4) * 8;

    auto stage = [&](int buf, int kt) {
        const bool seg = kt >= NKT / 2;
        const u16* __restrict__ Ab = seg ? A1 : A0;
        const int sA = seg ? sA1 : sA0;
        const int ka = (kt & (NKT / 2 - 1)) * BK;  // col within segment
        const int kb = kt * BK;                    // B is contiguous K=2048
        u16* Asb = &As[buf][0];
        u16* Bsb = &Bs[buf][0];
#pragma unroll
        for (int j = 0; j < AG; ++j) {
            const int c = j * 512 + tid;           // chunk 0..2047
            g2l16(Ab + (size_t)(bm * BM + (c >> 3)) * sA + ka + (c & 7) * 8,
                  Asb + (j * 512 + wave * 64) * 8);
        }
#pragma unroll
        for (int j = 0; j < BG; ++j) {
            const int c = j * 512 + tid;
            g2l16(Bw + (size_t)(bn * BN + (c >> 3)) * 2048 + kb + (c & 7) * 8,
                  Bsb + (j * 512 + wave * 64) * 8);
        }
    };

    auto compute = [&](int buf) {
        const u16* Asb = &As[buf][0];
        const u16* Bsb = &Bs[buf][0];
#pragma unroll
        for (int s = 0; s < 2; ++s) {
            bf16x8 af[FM], bv[FN];
#pragma unroll
            for (int i = 0; i < FM; ++i)
                af[i] = *(const bf16x8*)&Asb[(wr * PM + i * 16 + mr) * BK + s * 32 + q8];
#pragma unroll
            for (int j = 0; j < FN; ++j)
                bv[j] = *(const bf16x8*)&Bsb[(wc * PN + j * 16 + mr) * BK + s * 32 + q8];
#pragma unroll
            for (int i = 0; i < FM; ++i)
#pragma unroll
                for (int j = 0; j < FN; ++j)
                    acc[i][j] = __builtin_amdgcn_mfma_f32_16x16x32_bf16(
                        af[i], bv[j], acc[i][j], 0, 0, 0);
        }
    };

    stage(0, 0);
    __syncthreads();
    int cur = 0;
    for (int kt = 0; kt < NKT - 1; ++kt) {
        stage(cur ^ 1, kt + 1);   // next-tile loads fly under this tile's compute
        compute(cur);
        __syncthreads();          // single vmcnt(0)+lgkm drain + barrier per step
        cur ^= 1;
    }
    compute(cur);

    // epilogue: C/D layout col=lane&15, row=(lane>>4)*4+reg (m89/m91 verified)
    const int colBase = bn * BN + wc * PN + (lane & 15);
    const int rowBase = bm * BM + wr * PM + (lane >> 4) * 4;
    if constexpr (MODE == 0) {
        const bool is_r = (colBase < H_SZ);   // block-uniform (boundary 1024 % 256 == 0)
#pragma unroll
        for (int j = 0; j < FN; ++j) {
            const int coln = colBase + j * 16;
            const int cb = is_r ? coln : coln - H_SZ;
            const float bias = is_r ? (bx0[cb] + bh0[cb]) : (bx1[cb] + bh1[cb]);
#pragma unroll
            for (int i = 0; i < FM; ++i) {
#pragma unroll
                for (int r = 0; r < 4; ++r) {
                    const int rown = rowBase + i * 16 + r;
                    const size_t idx = (size_t)rown * H_SZ + cb;
                    const float v = acc[i][j][r] + bias;
                    const float sg = 1.0f / (1.0f + __expf(-v));
                    if (is_r) {
                        out_rh[idx] = f2bf(sg * hidden[idx]);
                    } else {
                        out_zf[idx] = sg;
                    }
                }
            }
        }
    } else {
#pragma unroll
        for (int j = 0; j < FN; ++j) {
            const int coln = colBase + j * 16;
            const float bias = bx0[coln] + bh0[coln];
#pragma unroll
            for (int i = 0; i < FM; ++i) {
#pragma unroll
                for (int r = 0; r < 4; ++r) {
                    const int rown = rowBase + i * 16 + r;
                    const size_t idx = (size_t)rown * H_SZ + coln;
                    const float v = acc[i][j][r] + bias;
                    const float ht = tanhf(v);
                    const float zz = zbuf[idx];
                    const float hh = hidden[idx];
                    out_f[idx] = zz * hh + (1.0f - zz) * ht;
                }
            }
        }
    }
}

// ---------------- row-wise log_softmax over H=1024 ----------------
__global__ __launch_bounds__(256) void lsm_kernel(const float* __restrict__ nh,
                                                  float* __restrict__ out) {
    const int row = blockIdx.x;
    const int tid = threadIdx.x;
    const int wave = tid >> 6, lane = tid & 63;
    const float4 v = ((const float4*)(nh + (size_t)row * H_SZ))[tid];
    __shared__ float redm[4];
    __shared__ float reds[4];
    float m = fmaxf(fmaxf(v.x, v.y), fmaxf(v.z, v.w));
#pragma unroll
    for (int o = 32; o; o >>= 1) m = fmaxf(m, __shfl_xor(m, o));
    if (lane == 0) redm[wave] = m;
    __syncthreads();
    const float M = fmaxf(fmaxf(redm[0], redm[1]), fmaxf(redm[2], redm[3]));
    float s = __expf(v.x - M) + __expf(v.y - M) + __expf(v.z - M) + __expf(v.w - M);
#pragma unroll
    for (int o = 32; o; o >>= 1) s += __shfl_xor(s, o);
    if (lane == 0) reds[wave] = s;
    __syncthreads();
    const float S = reds[0] + reds[1] + reds[2] + reds[3];
    const float lse = M + __logf(S);
    float4 ov;
    ov.x = v.x - lse; ov.y = v.y - lse; ov.z = v.z - lse; ov.w = v.w - lse;
    ((float4*)(out + (size_t)row * H_SZ))[tid] = ov;
}

extern "C" void kernel_launch(void* const* d_in, const int* in_sizes, int n_in,
                              void* d_out, int out_size, void* d_ws, size_t ws_size,
                              hipStream_t stream) {
    const float* input  = (const float*)d_in[0];
    const float* hidden = (const float*)d_in[1];
    const float* Wir = (const float*)d_in[2];  const float* bir = (const float*)d_in[3];
    const float* Whr = (const float*)d_in[4];  const float* bhr = (const float*)d_in[5];
    const float* Wiz = (const float*)d_in[6];  const float* biz = (const float*)d_in[7];
    const float* Whz = (const float*)d_in[8];  const float* bhz = (const float*)d_in[9];
    const float* Wih = (const float*)d_in[10]; const float* bih = (const float*)d_in[11];
    const float* Whh = (const float*)d_in[12]; const float* bhh = (const float*)d_in[13];

    // workspace layout (92 MB total)
    char* ws = (char*)d_ws;
    u16* Acat = (u16*)(ws);                     // 32 MB  [8192][2048] = [X | H]
    u16* Brz  = (u16*)(ws + (32u << 20));       //  8 MB  [2048][2048] = [[Wir|Whr],[Wiz|Whz]]
    u16* Bh   = (u16*)(ws + (40u << 20));       //  4 MB  [1024][2048] = [Wih|Whh]
    u16* RHb  = (u16*)(ws + (44u << 20));       // 16 MB  [8192][1024] r*hidden bf16
    float* Zf = (float*)(ws + (60u << 20));     // 32 MB  z f32

    float* out_lsm = (float*)d_out;
    float* out_nh  = (float*)d_out + (size_t)B_SZ * H_SZ;

    cvt_all<<<22528, 256, 0, stream>>>(
        input, hidden, Wir, Whr, Wiz, Whz, Wih, Whh, Acat, Brz, Bh);

    // fused r+z GEMM: M=8192 N=2048 K=2048, 256x256 tiles -> 8x32 = 256 blocks
    gemm2048<0, 256, 2><<<256, 512, 0, stream>>>(
        Acat, Acat + 1024, 2048, 2048, Brz,
        bir, bhr, biz, bhz, hidden, nullptr, RHb, Zf, nullptr);
    // h~ GEMM: M=8192 N=1024 K=2048 (X | RHb), 256x128 tiles -> 8x32 = 256 blocks
    gemm2048<2, 128, 1><<<256, 512, 0, stream>>>(
        Acat, RHb, 2048, 1024, Bh,
        bih, bhh, nullptr, nullptr, hidden, Zf, nullptr, nullptr, out_nh);

    lsm_kernel<<<B_SZ, 256, 0, stream>>>(out_nh, out_lsm);
}

// Round 5
// 332.500 us; speedup vs baseline: 1.1983x; 1.0313x over previous
//
#include <hip/hip_runtime.h>
#include <cstdint>

#define B_SZ 8192
#define IN_SZ 1024
#define H_SZ 1024

typedef unsigned short u16;
typedef __bf16 bf16_t;
typedef bf16_t bf16x8 __attribute__((ext_vector_type(8)));
typedef float floatx4 __attribute__((ext_vector_type(4)));

__device__ __forceinline__ u16 f2bf(float f) {
    unsigned int u = __float_as_uint(f);
    u += 0x7fffu + ((u >> 16) & 1u);   // RNE
    return (u16)(u >> 16);
}

__device__ __forceinline__ ushort4 cvt4(float4 v) {
    ushort4 o;
    o.x = f2bf(v.x); o.y = f2bf(v.y); o.z = f2bf(v.z); o.w = f2bf(v.w);
    return o;
}

// async global->LDS, 16B per lane; LDS dest = wave-uniform base + lane*16
__device__ __forceinline__ void g2l16(const u16* g, u16* l) {
    __builtin_amdgcn_global_load_lds(
        (__attribute__((address_space(1))) void*)(uintptr_t)g,
        (__attribute__((address_space(3))) void*)(uint32_t)(uintptr_t)l,
        16, 0, 0);
}

// phase boundary: pin order, counted vmcnt (NEVER 0 in steady state), raw barrier
template <int N>
__device__ __forceinline__ void phase_end() {
    __builtin_amdgcn_sched_barrier(0);
    if constexpr (N == 0) asm volatile("s_waitcnt vmcnt(0)" ::: "memory");
    else if constexpr (N == 3) asm volatile("s_waitcnt vmcnt(3)" ::: "memory");
    else if constexpr (N == 4) asm volatile("s_waitcnt vmcnt(4)" ::: "memory");
    else if constexpr (N == 6) asm volatile("s_waitcnt vmcnt(6)" ::: "memory");
    else if constexpr (N == 8) asm volatile("s_waitcnt vmcnt(8)" ::: "memory");
    __builtin_amdgcn_s_barrier();
    __builtin_amdgcn_sched_barrier(0);
}

// ---------------- fused fp32 -> bf16 conversion into K-concat layouts -----------
// Acat[8192][2048] = [bf16(input) | bf16(hidden)]
// Brz [2048][2048] = [[Wir|Whr],[Wiz|Whz]];  Bh [1024][2048] = [Wih|Whh]
__global__ __launch_bounds__(256) void cvt_all(
    const float* __restrict__ x, const float* __restrict__ h,
    const float* __restrict__ Wir, const float* __restrict__ Whr,
    const float* __restrict__ Wiz, const float* __restrict__ Whz,
    const float* __restrict__ Wih, const float* __restrict__ Whh,
    u16* __restrict__ Acat, u16* __restrict__ Brz, u16* __restrict__ Bh) {
    const int b = blockIdx.x;
    const int t = threadIdx.x;
    if (b < 8192) {
        float4 v = ((const float4*)(x + (size_t)b * 1024))[t];
        ((ushort4*)(Acat + (size_t)b * 2048))[t] = cvt4(v);
    } else if (b < 16384) {
        const int m = b - 8192;
        float4 v = ((const float4*)(h + (size_t)m * 1024))[t];
        ((ushort4*)(Acat + (size_t)m * 2048 + 1024))[t] = cvt4(v);
    } else {
        const int wb = b - 16384;   // 0..6143
        const int w = wb >> 10;
        const int n = wb & 1023;
        const float* src;
        u16* dst;
        switch (w) {
            case 0: src = Wir; dst = Brz + (size_t)n * 2048;               break;
            case 1: src = Whr; dst = Brz + (size_t)n * 2048 + 1024;        break;
            case 2: src = Wiz; dst = Brz + (size_t)(n + 1024) * 2048;      break;
            case 3: src = Whz; dst = Brz + (size_t)(n + 1024) * 2048 + 1024; break;
            case 4: src = Wih; dst = Bh + (size_t)n * 2048;                break;
            default: src = Whh; dst = Bh + (size_t)n * 2048 + 1024;        break;
        }
        float4 v = ((const float4*)(src + (size_t)n * 1024))[t];
        ((ushort4*)dst)[t] = cvt4(v);
    }
}

// ---------------- K=2048 NT GEMM, 4-deep ring + counted vmcnt + T2 swizzle ------
// BM=256, BK=32, 512 thr (8 waves). Ring of 4 LDS buffers (buf = t&3).
// During K-tile t: stage tile t+3 (buffer freed by barrier at end of t-1),
// compute tile t, then vmcnt(2*LS) [tile t+1 resident, t+2/t+3 in flight] + barrier.
// LDS layout (T2, rule #21 both-sides): 256B super-rows pairing rows (r>>1),
// 16B-unit within super-row = ((r&1)*4 + kslot) ^ ((r>>1)&7). Staged via
// inverse-permuted GLOBAL source + linear LDS dest; read with same XOR.
// -> 2 lanes/bank on ds_read_b128 (free), vs 8-way unswizzled.
// MODE 0 (r+z, N=2048): col<1024 -> out_rh=bf16(sigmoid(C+b)*hidden);
//                       col>=1024 -> out_zf[.,c-1024]=sigmoid(C+b)
// MODE 2 (h~, N=1024): ht=tanh(C+b); out_f = z*hidden + (1-z)*ht
template <int MODE, int BN, int WN>
__global__ __launch_bounds__(512) void gemm8p(
    const u16* __restrict__ A0, const u16* __restrict__ A1,
    const int sA0, const int sA1,
    const u16* __restrict__ Bw,
    const float* __restrict__ bx0, const float* __restrict__ bh0,
    const float* __restrict__ bx1, const float* __restrict__ bh1,
    const float* __restrict__ hidden, const float* __restrict__ zbuf,
    u16* __restrict__ out_rh, float* __restrict__ out_zf,
    float* __restrict__ out_f) {
    constexpr int BM = 256, BK = 32, NKT = 64;      // K = 2048
    constexpr int WM = 8 / WN, PM = BM / WM, PN = BN / WN;   // PN == 64
    constexpr int FM = PM / 16, FN = PN / 16;                // FN == 4
    constexpr int AG = 2, BG = BN / 128;    // 16B chunks per thread per tile
    constexpr int LS = AG + BG;             // loads/thread/tile: 4 (BN256) or 3

    __shared__ u16 As[4][BM * BK];          // 4 x 16 KB
    __shared__ u16 Bs[4][BN * BK];          // 4 x 16/8 KB

    const int tid = threadIdx.x;
    const int wave = tid >> 6;
    const int lane = tid & 63;
    // chunked XCD swizzle (nwg = 256 for both modes; 8 bn-blocks each)
    const int wid = blockIdx.x;
    const int swz = (wid & 7) * 32 + (wid >> 3);
    const int bn = swz & 7;
    const int bm = swz >> 3;
    const int wc = wave & (WN - 1);
    const int wr = wave / WN;

    const floatx4 z4 = {0.f, 0.f, 0.f, 0.f};
    floatx4 acc[FM][FN];
#pragma unroll
    for (int i = 0; i < FM; ++i)
#pragma unroll
        for (int j = 0; j < FN; ++j) acc[i][j] = z4;

    // ---- staging source coords (inverse swizzle on global address) ----
    // physical chunk c: super=c>>3, unitp=c&7; logical unit=unitp^(super&7);
    // row = 2*super + (unit>>2); k-offset = (unit&3)*8
    int rowA[AG], gkA[AG], rowB[BG], gkB[BG];
#pragma unroll
    for (int j = 0; j < AG; ++j) {
        const int c = j * 512 + tid;
        const int sup = c >> 3;
        const int u = (c & 7) ^ (sup & 7);
        rowA[j] = sup * 2 + (u >> 2);
        gkA[j] = (u & 3) * 8;
    }
#pragma unroll
    for (int j = 0; j < BG; ++j) {
        const int c = j * 512 + tid;
        const int sup = c >> 3;
        const int u = (c & 7) ^ (sup & 7);
        rowB[j] = sup * 2 + (u >> 2);
        gkB[j] = (u & 3) * 8;
    }

    // ---- swizzled ds_read bases (u16 idx): frag i at base + i*512 ----
    const int mr = lane & 15;
    const int sg = lane >> 4;               // k-slot 0..3
    const int R0 = wr * PM + mr;
    const int baseA = (R0 >> 1) * 64 + (((((R0 & 1) << 2) | sg) ^ ((R0 >> 1) & 7)) << 3);
    const int C0 = wc * PN + mr;
    const int baseB = (C0 >> 1) * 64 + (((((C0 & 1) << 2) | sg) ^ ((C0 >> 1) & 7)) << 3);

    auto stage = [&](int t) {
        const int buf = t & 3;
        const bool seg = t >= NKT / 2;
        const u16* __restrict__ Ab = seg ? A1 : A0;
        const int sA = seg ? sA1 : sA0;
        const int ka = (t & (NKT / 2 - 1)) * BK;
        const int kb = t * BK;
        u16* Asb = &As[buf][0];
        u16* Bsb = &Bs[buf][0];
#pragma unroll
        for (int j = 0; j < AG; ++j)
            g2l16(Ab + (size_t)(bm * BM + rowA[j]) * sA + ka + gkA[j],
                  Asb + (j * 512 + wave * 64) * 8);
#pragma unroll
        for (int j = 0; j < BG; ++j)
            g2l16(Bw + (size_t)(bn * BN + rowB[j]) * 2048 + kb + gkB[j],
                  Bsb + (j * 512 + wave * 64) * 8);
    };

    auto compute = [&](int t) {
        const u16* Asb = &As[t & 3][0];
        const u16* Bsb = &Bs[t & 3][0];
        bf16x8 af[FM], bv[FN];
#pragma unroll
        for (int i = 0; i < FM; ++i)
            af[i] = *(const bf16x8*)&Asb[baseA + i * 512];
#pragma unroll
        for (int j = 0; j < FN; ++j)
            bv[j] = *(const bf16x8*)&Bsb[baseB + j * 512];
        __builtin_amdgcn_s_setprio(1);
#pragma unroll
        for (int i = 0; i < FM; ++i)
#pragma unroll
            for (int j = 0; j < FN; ++j)
                acc[i][j] = __builtin_amdgcn_mfma_f32_16x16x32_bf16(
                    af[i], bv[j], acc[i][j], 0, 0, 0);
        __builtin_amdgcn_s_setprio(0);
    };

    // prologue: 3 tiles in flight
    stage(0); stage(1); stage(2);
    phase_end<2 * LS>();                 // S(0) resident
#pragma unroll 4
    for (int t = 0; t < NKT - 3; ++t) {  // t = 0..60
        stage(t + 3);
        compute(t);
        phase_end<2 * LS>();             // S(t+1) resident; t+2,t+3 in flight
    }
    compute(NKT - 3); phase_end<LS>();   // S(62) resident
    compute(NKT - 2); phase_end<0>();    // S(63) resident
    compute(NKT - 1);

    // epilogue: C/D layout col=lane&15, row=(lane>>4)*4+reg (m89/m91 verified)
    const int colBase = bn * BN + wc * PN + (lane & 15);
    const int rowBase = bm * BM + wr * PM + (lane >> 4) * 4;
    if constexpr (MODE == 0) {
        const bool is_r = (colBase < H_SZ);   // block-uniform (1024 % 256 == 0)
#pragma unroll
        for (int j = 0; j < FN; ++j) {
            const int coln = colBase + j * 16;
            const int cb = is_r ? coln : coln - H_SZ;
            const float bias = is_r ? (bx0[cb] + bh0[cb]) : (bx1[cb] + bh1[cb]);
#pragma unroll
            for (int i = 0; i < FM; ++i) {
#pragma unroll
                for (int r = 0; r < 4; ++r) {
                    const int rown = rowBase + i * 16 + r;
                    const size_t idx = (size_t)rown * H_SZ + cb;
                    const float v = acc[i][j][r] + bias;
                    const float sg2 = 1.0f / (1.0f + __expf(-v));
                    if (is_r) {
                        out_rh[idx] = f2bf(sg2 * hidden[idx]);
                    } else {
                        out_zf[idx] = sg2;
                    }
                }
            }
        }
    } else {
#pragma unroll
        for (int j = 0; j < FN; ++j) {
            const int coln = colBase + j * 16;
            const float bias = bx0[coln] + bh0[coln];
#pragma unroll
            for (int i = 0; i < FM; ++i) {
#pragma unroll
                for (int r = 0; r < 4; ++r) {
                    const int rown = rowBase + i * 16 + r;
                    const size_t idx = (size_t)rown * H_SZ + coln;
                    const float v = acc[i][j][r] + bias;
                    const float ht = tanhf(v);
                    const float zz = zbuf[idx];
                    const float hh = hidden[idx];
                    out_f[idx] = zz * hh + (1.0f - zz) * ht;
                }
            }
        }
    }
}

// ---------------- row-wise log_softmax over H=1024 ----------------
__global__ __launch_bounds__(256) void lsm_kernel(const float* __restrict__ nh,
                                                  float* __restrict__ out) {
    const int row = blockIdx.x;
    const int tid = threadIdx.x;
    const int wave = tid >> 6, lane = tid & 63;
    const float4 v = ((const float4*)(nh + (size_t)row * H_SZ))[tid];
    __shared__ float redm[4];
    __shared__ float reds[4];
    float m = fmaxf(fmaxf(v.x, v.y), fmaxf(v.z, v.w));
#pragma unroll
    for (int o = 32; o; o >>= 1) m = fmaxf(m, __shfl_xor(m, o));
    if (lane == 0) redm[wave] = m;
    __syncthreads();
    const float M = fmaxf(fmaxf(redm[0], redm[1]), fmaxf(redm[2], redm[3]));
    float s = __expf(v.x - M) + __expf(v.y - M) + __expf(v.z - M) + __expf(v.w - M);
#pragma unroll
    for (int o = 32; o; o >>= 1) s += __shfl_xor(s, o);
    if (lane == 0) reds[wave] = s;
    __syncthreads();
    const float S = reds[0] + reds[1] + reds[2] + reds[3];
    const float lse = M + __logf(S);
    float4 ov;
    ov.x = v.x - lse; ov.y = v.y - lse; ov.z = v.z - lse; ov.w = v.w - lse;
    ((float4*)(out + (size_t)row * H_SZ))[tid] = ov;
}

extern "C" void kernel_launch(void* const* d_in, const int* in_sizes, int n_in,
                              void* d_out, int out_size, void* d_ws, size_t ws_size,
                              hipStream_t stream) {
    const float* input  = (const float*)d_in[0];
    const float* hidden = (const float*)d_in[1];
    const float* Wir = (const float*)d_in[2];  const float* bir = (const float*)d_in[3];
    const float* Whr = (const float*)d_in[4];  const float* bhr = (const float*)d_in[5];
    const float* Wiz = (const float*)d_in[6];  const float* biz = (const float*)d_in[7];
    const float* Whz = (const float*)d_in[8];  const float* bhz = (const float*)d_in[9];
    const float* Wih = (const float*)d_in[10]; const float* bih = (const float*)d_in[11];
    const float* Whh = (const float*)d_in[12]; const float* bhh = (const float*)d_in[13];

    // workspace layout (92 MB total)
    char* ws = (char*)d_ws;
    u16* Acat = (u16*)(ws);                     // 32 MB  [8192][2048] = [X | H]
    u16* Brz  = (u16*)(ws + (32u << 20));       //  8 MB  [2048][2048]
    u16* Bh   = (u16*)(ws + (40u << 20));       //  4 MB  [1024][2048]
    u16* RHb  = (u16*)(ws + (44u << 20));       // 16 MB  [8192][1024] r*hidden bf16
    float* Zf = (float*)(ws + (60u << 20));     // 32 MB  z f32

    float* out_lsm = (float*)d_out;
    float* out_nh  = (float*)d_out + (size_t)B_SZ * H_SZ;

    cvt_all<<<22528, 256, 0, stream>>>(
        input, hidden, Wir, Whr, Wiz, Whz, Wih, Whh, Acat, Brz, Bh);

    // fused r+z GEMM: M=8192 N=2048 K=2048, 256x256 tiles -> 256 blocks
    gemm8p<0, 256, 4><<<256, 512, 0, stream>>>(
        Acat, Acat + 1024, 2048, 2048, Brz,
        bir, bhr, biz, bhz, hidden, nullptr, RHb, Zf, nullptr);
    // h~ GEMM: M=8192 N=1024 K=2048 (X | RHb), 256x128 tiles -> 256 blocks
    gemm8p<2, 128, 2><<<256, 512, 0, stream>>>(
        Acat, RHb, 2048, 1024, Bh,
        bih, bhh, nullptr, nullptr, hidden, Zf, nullptr, nullptr, out_nh);

    lsm_kernel<<<B_SZ, 256, 0, stream>>>(out_nh, out_lsm);
}